// Round 1
// baseline (3967.901 us; speedup 1.0000x reference)
//
#include <hip/hip_runtime.h>

// Farthest Point Sampling: B=16 batches, N=65536 points, S=2048 samples.
// Output: gathered coords (B, S, 3) fp32.
//
// Design: 16 blocks per batch x 256 threads; each thread holds 16 points
// (x,y,z,closest) in registers. Per iteration: register distance+min update,
// block argmax via packed u64 keys, inter-block exchange through seq-tagged
// slots in d_ws (agent-scope atomics, double-buffered by parity; poison
// 0xAAAA never matches a valid seq 1..2048 so no init required).
//
// Arithmetic matches numpy bit-exactly: no FMA (__f*_rn), sum order
// ((dx*dx+dy*dy)+dz*dz), fminf, first-occurrence argmax via inverted-index
// packed key.

#define BATCHES 16
#define NPTS    65536
#define NSAMP   2048
#define PB      16            // blocks per batch
#define TPB     256           // threads per block
#define PPT     (NPTS / (PB * TPB))  // 16 points per thread

__global__ __launch_bounds__(TPB) void fps_kernel(
    const float* __restrict__ coords,
    float* __restrict__ out,
    unsigned long long* __restrict__ slots) {
  const int blk  = blockIdx.x;
  const int b    = blk >> 4;    // batch
  const int r    = blk & 15;    // rank within batch
  const int t    = threadIdx.x;
  const int lane = t & 63;
  const int wave = t >> 6;

  const float* __restrict__ cb = coords + (size_t)b * NPTS * 3;
  const int base = r * (TPB * PPT);

  // Register-resident points and closest-distance array.
  float px[PPT], py[PPT], pz[PPT], cl[PPT];
#pragma unroll
  for (int k = 0; k < PPT; ++k) {
    int idx = base + k * TPB + t;
    px[k] = cb[3 * idx + 0];
    py[k] = cb[3 * idx + 1];
    pz[k] = cb[3 * idx + 2];
    cl[k] = __builtin_inff();
  }

  __shared__ unsigned long long s_wred[TPB / 64];
  __shared__ float s_x, s_y, s_z;

  // Initial selected point: index 0 (deterministic start, matches reference).
  float sx = cb[0], sy = cb[1], sz = cb[2];

  for (int it = 0; it < NSAMP; ++it) {
    // --- distance update + per-thread argmax (ascending idx => '>' keeps
    // first occurrence within thread) ---
    float bestv = -1.0f;
    int bestk = 0;
#pragma unroll
    for (int k = 0; k < PPT; ++k) {
      float dx = __fsub_rn(sx, px[k]);
      float dy = __fsub_rn(sy, py[k]);
      float dz = __fsub_rn(sz, pz[k]);
      float d  = __fadd_rn(__fadd_rn(__fmul_rn(dx, dx), __fmul_rn(dy, dy)),
                           __fmul_rn(dz, dz));
      float c  = fminf(cl[k], d);
      cl[k] = c;
      if (c > bestv) { bestv = c; bestk = k; }
    }
    int bestidx = base + bestk * TPB + t;
    // Packed key: monotonic float bits (distances >= 0) | inverted index
    // (ties -> smallest index = numpy first occurrence).
    unsigned long long key =
        ((unsigned long long)__float_as_uint(bestv) << 32) |
        (unsigned long long)(65535 - bestidx);

    // --- wave butterfly max ---
#pragma unroll
    for (int off = 32; off > 0; off >>= 1) {
      unsigned long long o = __shfl_xor(key, off, 64);
      if (o > key) key = o;
    }
    if (lane == 0) s_wred[wave] = key;
    __syncthreads();

    const int p = (it + 1) & 1;  // parity double-buffer
    unsigned long long* batch_slots = slots + ((size_t)p * BATCHES + b) * PB;

    // --- block winner -> publish slot (val|inv_idx|seq) ---
    if (t == 0) {
      unsigned long long bk = s_wred[0];
#pragma unroll
      for (int w = 1; w < TPB / 64; ++w) {
        unsigned long long o = s_wred[w];
        if (o > bk) bk = o;
      }
      unsigned long long slotval = (bk & 0xFFFFFFFF00000000ull) |
                                   ((bk & 0xFFFFull) << 16) |
                                   (unsigned long long)(it + 1);
      __hip_atomic_store(batch_slots + r, slotval, __ATOMIC_RELAXED,
                         __HIP_MEMORY_SCOPE_AGENT);
    }

    // --- poll peers, prefetch candidate coords, reduce, broadcast ---
    if (wave == 0) {
      unsigned long long k48 = 0;
      float gx = 0.f, gy = 0.f, gz = 0.f;
      if (lane < PB) {
        const unsigned long long want = (unsigned long long)(it + 1);
        unsigned long long v;
        do {
          v = __hip_atomic_load(batch_slots + lane, __ATOMIC_RELAXED,
                                __HIP_MEMORY_SCOPE_AGENT);
        } while ((v & 0xFFFFull) != want);
        k48 = v >> 16;  // valbits(32) . inv_idx(16)
        int wi = 65535 - (int)(k48 & 0xFFFFull);
        // Prefetch this candidate's coords; hidden behind the butterfly.
        gx = cb[3 * wi + 0];
        gy = cb[3 * wi + 1];
        gz = cb[3 * wi + 2];
      }
      unsigned long long m = k48;
#pragma unroll
      for (int off = 32; off > 0; off >>= 1) {
        unsigned long long o = __shfl_xor(m, off, 64);
        if (o > m) m = o;
      }
      // Unique winner (block index ranges are disjoint -> unique inv_idx).
      if (lane < PB && k48 == m) {
        s_x = gx; s_y = gy; s_z = gz;
        if (r == 0) {
          float* op = out + ((size_t)b * NSAMP + it) * 3;
          op[0] = gx; op[1] = gy; op[2] = gz;
        }
      }
    }
    __syncthreads();
    sx = s_x; sy = s_y; sz = s_z;
  }
}

extern "C" void kernel_launch(void* const* d_in, const int* in_sizes, int n_in,
                              void* d_out, int out_size, void* d_ws,
                              size_t ws_size, hipStream_t stream) {
  const float* coords = (const float*)d_in[0];  // (16, 65536, 3) fp32
  // d_in[1] (features) is unused by the reference output.
  float* out = (float*)d_out;                   // (16, 2048, 3) fp32
  unsigned long long* slots = (unsigned long long*)d_ws;  // 2*16*16*8 = 4 KiB
  fps_kernel<<<dim3(BATCHES * PB), dim3(TPB), 0, stream>>>(coords, out, slots);
}